// Round 1
// 189.173 us; speedup vs baseline: 1.0497x; 1.0497x over previous
//
#include <hip/hip_runtime.h>
#include <hip/hip_bf16.h>
#include <stdint.h>

// bf16 MFMA pipeline, v6. B=2, L=2048, D=1024, H=16, dh=64.
// a2 = softmax(s_prev) is a column permutation of a1 -> o = lam * A1 @ (v - roll(v,-1)).
// v6: same S^T/P^T-in-register flash as v5, but 8 waves/block (512 thr) with the
// j (key) dimension split across wave pairs (jw = wave>>2). Same grid (16,32),
// same global/LDS traffic per block, 2x resident waves/CU (occupancy 17%->~34%).
// Cross-jw Ot/lacc reduction through LDS once at the end.

typedef __attribute__((ext_vector_type(8))) short s16x8;
typedef __attribute__((ext_vector_type(4))) short s16x4;
typedef __attribute__((ext_vector_type(4))) float f32x4;

__device__ __forceinline__ float bf2f(unsigned short u) {
    union { unsigned int i; float f; } x; x.i = ((unsigned int)u) << 16; return x.f;
}
__device__ __forceinline__ unsigned short f2bf(float f) {
    union { float f; unsigned int i; } x; x.f = f;
    unsigned int r = x.i + 0x7FFFu + ((x.i >> 16) & 1u);   // RNE
    return (unsigned short)(r >> 16);
}

__device__ __forceinline__ f32x4 mfma16(s16x4 a, s16x4 b, f32x4 c) {
#if __has_builtin(__builtin_amdgcn_mfma_f32_16x16x16bf16_1k)
    return __builtin_amdgcn_mfma_f32_16x16x16bf16_1k(a, b, c, 0, 0, 0);
#else
    f32x4 d;
    asm volatile("v_mfma_f32_16x16x16_bf16 %0, %1, %2, %3\n\ts_nop 7\n\ts_nop 3"
                 : "=v"(d) : "v"(a), "v"(b), "v"(c));
    return d;
#endif
}

// async global->LDS, 16B/lane; LDS dest = wave-uniform base + lane*16
__device__ __forceinline__ void gload16(const void* g, void* l) {
    auto gp = reinterpret_cast<const __attribute__((address_space(1))) unsigned int*>(
        reinterpret_cast<uintptr_t>(g));
    auto lp = reinterpret_cast<__attribute__((address_space(3))) unsigned int*>(
        reinterpret_cast<uintptr_t>(l));
    __builtin_amdgcn_global_load_lds(gp, lp, 16, 0, 0);
}

__global__ __launch_bounds__(256) void cvt_all(
    const float* __restrict__ x, const float* __restrict__ wq,
    const float* __restrict__ wo,
    unsigned short* __restrict__ xb, unsigned short* __restrict__ wqb,
    unsigned short* __restrict__ wob)
{
    int i4 = blockIdx.x * 256 + threadIdx.x;   // float4 index
    const float* src; unsigned short* dst; int off;
    if (i4 < 1048576)            { src = x;  dst = xb;  off = i4; }
    else if (i4 < 1048576 + 786432) { src = wq; dst = wqb; off = i4 - 1048576; }
    else                         { src = wo; dst = wob; off = i4 - 1835008; }
    float4 v = ((const float4*)src)[off];
    ushort4 u;
    u.x = f2bf(v.x); u.y = f2bf(v.y); u.z = f2bf(v.z); u.w = f2bf(v.w);
    ((ushort4*)dst)[off] = u;
}

// vdt[b][h][dh][L] = v[b, j, h, dh] - v[b, (j+1)%L, h, dh], transposed via LDS.
__global__ __launch_bounds__(256) void vd_transpose(
    const unsigned short* __restrict__ qkvb, unsigned short* __restrict__ vdt)
{
    __shared__ unsigned short T[64][72];
    const int tid = threadIdx.x;
    const int j0 = blockIdx.x * 64;
    const int bh = blockIdx.y, b = bh >> 4, h = bh & 15;
    const unsigned short* vb = qkvb + (size_t)b * 2048 * 3072 + 2048 + h * 64;

    int r = tid >> 2, cq = tid & 3;
    int j = j0 + r, jn = (j + 1) & 2047;
    const unsigned short* p0 = vb + (size_t)j  * 3072 + cq * 16;
    const unsigned short* p1 = vb + (size_t)jn * 3072 + cq * 16;
    s16x8 a0 = *(const s16x8*)p0, a1 = *(const s16x8*)(p0 + 8);
    s16x8 b0 = *(const s16x8*)p1, b1 = *(const s16x8*)(p1 + 8);
#pragma unroll
    for (int u = 0; u < 8; ++u)
        T[cq * 16 + u][r] = f2bf(bf2f((unsigned short)a0[u]) - bf2f((unsigned short)b0[u]));
#pragma unroll
    for (int u = 0; u < 8; ++u)
        T[cq * 16 + 8 + u][r] = f2bf(bf2f((unsigned short)a1[u]) - bf2f((unsigned short)b1[u]));
    __syncthreads();

    int row = tid >> 2, sc = tid & 3;
    s16x8 o0 = *(const s16x8*)&T[row][sc * 16];
    s16x8 o1 = *(const s16x8*)&T[row][sc * 16 + 8];
    unsigned short* dst = vdt + ((size_t)bh * 64 + row) * 2048 + j0 + sc * 16;
    *(s16x8*)dst = o0;
    *(s16x8*)(dst + 8) = o1;
}

// C[m,n] = sum_k A[m,k]*Bm[n,k] + bias[n]; cols < nscale additionally *= smul.
template <int OUT_BF16, int BN>
__global__ __launch_bounds__(256) void gemm_nt_mfma(
    const unsigned short* __restrict__ A,
    const unsigned short* __restrict__ Bm,
    const float* __restrict__ bias,
    void* __restrict__ C,
    int M, int N, int K, int nscale, float smul)
{
    constexpr int NT = BN / 32;
    __shared__ unsigned short As[2][128][32];
    __shared__ unsigned short Bs[2][BN][32];

    const int tid = threadIdx.x;
    const int wave = tid >> 6, lane = tid & 63;
    const int quad = lane >> 4, ln = lane & 15;
    const int wm = (wave >> 1) * 64, wn = (wave & 1) * (NT * 16);
    const int m0 = blockIdx.y * 128, n0 = blockIdx.x * BN;
    const int rA = wave * 16 + (lane >> 2);
    const int gsl = lane & 3;

    f32x4 acc[4][NT];
#pragma unroll
    for (int mt = 0; mt < 4; ++mt)
#pragma unroll
        for (int nt = 0; nt < NT; ++nt) acc[mt][nt] = f32x4{0.f, 0.f, 0.f, 0.f};

    auto stage = [&](int p, int k0) {
#pragma unroll
        for (int q = 0; q < 2; ++q) {
            int row = q * 64 + rA;
            int kg = gsl ^ ((row >> 1) & 3);
            gload16(A + (size_t)(m0 + row) * K + k0 + kg * 8,
                    &As[p][q * 64 + wave * 16][0]);
            if (q * 64 < BN)
                gload16(Bm + (size_t)(n0 + row) * K + k0 + kg * 8,
                        &Bs[p][q * 64 + wave * 16][0]);
        }
    };

    stage(0, 0);
    __syncthreads();
    int p = 0;
    for (int k0 = 0; k0 < K; k0 += 32) {
        if (k0 + 32 < K) stage(p ^ 1, k0 + 32);
        s16x8 af[4], bfr[NT];
#pragma unroll
        for (int mt = 0; mt < 4; ++mt) {
            int rr = wm + mt * 16 + ln;
            af[mt] = *(const s16x8*)&As[p][rr][((quad ^ ((rr >> 1) & 3)) & 3) * 8];
        }
#pragma unroll
        for (int nt = 0; nt < NT; ++nt) {
            int rr = wn + nt * 16 + ln;
            bfr[nt] = *(const s16x8*)&Bs[p][rr][((quad ^ ((rr >> 1) & 3)) & 3) * 8];
        }
#pragma unroll
        for (int mt = 0; mt < 4; ++mt)
#pragma unroll
            for (int nt = 0; nt < NT; ++nt)
                acc[mt][nt] = __builtin_amdgcn_mfma_f32_16x16x32_bf16(
                    af[mt], bfr[nt], acc[mt][nt], 0, 0, 0);
        __syncthreads();
        p ^= 1;
    }

    float bb[NT];
#pragma unroll
    for (int nt = 0; nt < NT; ++nt) bb[nt] = bias[n0 + wn + nt * 16 + ln];
#pragma unroll
    for (int mt = 0; mt < 4; ++mt)
#pragma unroll
        for (int nt = 0; nt < NT; ++nt) {
            int col = n0 + wn + nt * 16 + ln;
            float sc = (col < nscale) ? smul : 1.f;
#pragma unroll
            for (int rg = 0; rg < 4; ++rg) {
                int row = m0 + wm + mt * 16 + quad * 4 + rg;
                float v = (acc[mt][nt][rg] + bb[nt]) * sc;
                if (OUT_BF16)
                    ((unsigned short*)C)[(size_t)row * N + col] = f2bf(v);
                else
                    ((float*)C)[(size_t)row * N + col] = v;
            }
        }
}

// Differential attention, v6: 8 waves (512 thr). wave = jw*4+qw.
// qw owns 32 q-rows; jw in {0,1} owns a 32-row j-half of each 64-row K/V chunk.
// Same per-block MFMA/LDS/global traffic as v5, 2x resident waves.
__global__ __launch_bounds__(512) void diff_attn_v6(
    const unsigned short* __restrict__ qkv,   // [B*L][3072] bf16 (Q pre-scaled by log2e/32)
    const unsigned short* __restrict__ vdt,   // [B*H][64][2048] bf16
    const float* __restrict__ lam_p,
    unsigned short* __restrict__ o_ws)        // [B*L][1024] bf16
{
    constexpr int L = 2048, TD = 3072;

    __shared__ unsigned short Ks[2][64][64];  // [seq][dh], chunk-swizzled
    __shared__ unsigned short Vs[2][64][64];  // [dh][seq], chunk-swizzled
    __shared__ f32x4 Red[4][2][4][64];        // cross-jw Ot reduce: [qw][s][mt][lane]
    __shared__ float Lred[4][2][64];          // cross-jw lacc reduce

    const int tid = threadIdx.x;
    const int wave = tid >> 6, lane = tid & 63;
    const int qw = wave & 3, jw = wave >> 2;
    const int quad = lane >> 4, ln = lane & 15;
    const int bh = blockIdx.y, b = bh >> 4, h = bh & 15;
    const int q0 = blockIdx.x * 128;
    const size_t seqbase = (size_t)b * L;
    const unsigned short* base = qkv + seqbase * TD + h * 64;
    const unsigned short* kb = base + 1024;
    const unsigned short* vbase = vdt + (size_t)bh * 64 * 2048;

    const int lsl = lane >> 3;
    const int cgl = (lane & 7) ^ lsl;

    // Q fragments (layout serves as MFMA B-operand: n=ln -> q, k=quad*8+u -> d)
    s16x8 qf[2][2];
#pragma unroll
    for (int s = 0; s < 2; ++s) {
        const unsigned short* qrow =
            base + (size_t)(q0 + qw * 32 + s * 16 + ln) * TD;
        qf[s][0] = *(const s16x8*)(qrow + quad * 8);
        qf[s][1] = *(const s16x8*)(qrow + 32 + quad * 8);
    }

    // each of 8 waves stages 8 rows of K and 8 rows of Vd^T (1 KiB each)
    auto stage = [&](int p, int j0) {
        const unsigned short* k0p = kb + (size_t)(j0 + wave * 8 + lsl) * TD + cgl * 8;
        gload16(k0p, &Ks[p][wave * 8][0]);
        const unsigned short* v0p = vbase + (size_t)(wave * 8 + lsl) * 2048 + j0 + cgl * 8;
        gload16(v0p, &Vs[p][wave * 8][0]);
    };

    f32x4 Ot[2][4];    // O^T accumulators: q=ln, d = mt*16 + quad*4 + rg
    f32x4 lacc[2];     // row-sum accumulators via ones-MFMA (all rg equal)
#pragma unroll
    for (int s = 0; s < 2; ++s) {
        lacc[s] = f32x4{0.f, 0.f, 0.f, 0.f};
#pragma unroll
        for (int mt = 0; mt < 4; ++mt) Ot[s][mt] = f32x4{0.f, 0.f, 0.f, 0.f};
    }

    const s16x4 ones = {(short)0x3F80, (short)0x3F80, (short)0x3F80, (short)0x3F80};
    const int kx0 = (quad ^ (ln & 7)) << 3;
    const int kx1 = ((quad + 4) ^ (ln & 7)) << 3;

    stage(0, 0);
    __syncthreads();
    int p = 0;
    for (int kt = 0; kt < 32; ++kt) {
        if (kt + 1 < 32) stage(p ^ 1, (kt + 1) * 64);

        // ---- S^T = K Q^T over this wave's j-half (t2 = jw*2 + t, t in {0,1}) ----
        // A = K-frag (m=j), B = qf (n=q). C: col=ln->q, row=quad*4+rg->j
        f32x4 ST[2][2];
#pragma unroll
        for (int t = 0; t < 2; ++t) {
            const int t2 = jw * 2 + t;
            s16x8 k0 = *(const s16x8*)&Ks[p][t2 * 16 + ln][kx0];
            s16x8 k1 = *(const s16x8*)&Ks[p][t2 * 16 + ln][kx1];
#pragma unroll
            for (int s = 0; s < 2; ++s) {
                f32x4 z = f32x4{0.f, 0.f, 0.f, 0.f};
                z = __builtin_amdgcn_mfma_f32_16x16x32_bf16(k0, qf[s][0], z, 0, 0, 0);
                z = __builtin_amdgcn_mfma_f32_16x16x32_bf16(k1, qf[s][1], z, 0, 0, 0);
                ST[s][t] = z;
            }
        }

        // ---- P^T = exp2(S^T) packed to bf16 in-register: B-frag of 16x16x16 ----
        s16x4 pf[2][2];
#pragma unroll
        for (int s = 0; s < 2; ++s)
#pragma unroll
            for (int t = 0; t < 2; ++t) {
                unsigned int b0 = __builtin_bit_cast(unsigned int,
                    __builtin_amdgcn_exp2f(ST[s][t][0]));
                unsigned int b1 = __builtin_bit_cast(unsigned int,
                    __builtin_amdgcn_exp2f(ST[s][t][1]));
                unsigned int b2 = __builtin_bit_cast(unsigned int,
                    __builtin_amdgcn_exp2f(ST[s][t][2]));
                unsigned int b3 = __builtin_bit_cast(unsigned int,
                    __builtin_amdgcn_exp2f(ST[s][t][3]));
                unsigned int lo = (b0 >> 16) | (b1 & 0xFFFF0000u);
                unsigned int hi = (b2 >> 16) | (b3 & 0xFFFF0000u);
                uint2 pk = make_uint2(lo, hi);
                pf[s][t] = __builtin_bit_cast(s16x4, pk);
            }

        // ---- partial row sums l[q] += sum_j P^T[j][q] via ones-MFMA ----
#pragma unroll
        for (int s = 0; s < 2; ++s)
#pragma unroll
            for (int t = 0; t < 2; ++t)
                lacc[s] = mfma16(ones, pf[s][t], lacc[s]);

        // ---- O^T += Vd^T P^T over this wave's j-half ----
#pragma unroll
        for (int t = 0; t < 2; ++t) {
            const int t2 = jw * 2 + t;
#pragma unroll
            for (int mt = 0; mt < 4; ++mt) {
                int chunk = (2 * t2 + (quad >> 1)) ^ (ln & 7);
                s16x4 vf = *(const s16x4*)&Vs[p][mt * 16 + ln][chunk * 8 + (quad & 1) * 4];
#pragma unroll
                for (int s = 0; s < 2; ++s)
                    Ot[s][mt] = mfma16(vf, pf[s][t], Ot[s][mt]);
            }
        }
        __syncthreads();
        p ^= 1;
    }

    // ---- cross-jw reduction through LDS, then epilogue by jw==0 waves ----
    if (jw == 1) {
#pragma unroll
        for (int s = 0; s < 2; ++s) {
            Lred[qw][s][lane] = lacc[s][0];
#pragma unroll
            for (int mt = 0; mt < 4; ++mt) Red[qw][s][mt][lane] = Ot[s][mt];
        }
    }
    __syncthreads();
    if (jw == 0) {
        const float lam = lam_p[0];
#pragma unroll
        for (int s = 0; s < 2; ++s) {
            float lsum = lacc[s][0] + Lred[qw][s][lane];
            float inv = lam / lsum;
            int row = q0 + qw * 32 + s * 16 + ln;
            unsigned short* orow = o_ws + (seqbase + row) * 1024 + h * 64 + quad * 4;
#pragma unroll
            for (int mt = 0; mt < 4; ++mt) {
                f32x4 r = Red[qw][s][mt][lane];
                ushort4 u;
                u.x = f2bf((Ot[s][mt][0] + r[0]) * inv);
                u.y = f2bf((Ot[s][mt][1] + r[1]) * inv);
                u.z = f2bf((Ot[s][mt][2] + r[2]) * inv);
                u.w = f2bf((Ot[s][mt][3] + r[3]) * inv);
                *(ushort4*)(orow + mt * 16) = u;
            }
        }
    }
}

extern "C" void kernel_launch(void* const* d_in, const int* in_sizes, int n_in,
                              void* d_out, int out_size, void* d_ws, size_t ws_size,
                              hipStream_t stream) {
    const float* x     = (const float*)d_in[0];
    const float* w_qkv = (const float*)d_in[1];
    const float* b_qkv = (const float*)d_in[2];
    const float* w_out = (const float*)d_in[3];
    const float* b_out = (const float*)d_in[4];
    const float* lam   = (const float*)d_in[5];
    float* out = (float*)d_out;

    unsigned short* xb   = (unsigned short*)d_ws;
    unsigned short* wqb  = xb   + (size_t)4096 * 1024;
    unsigned short* wob  = wqb  + (size_t)3072 * 1024;
    unsigned short* qkvb = wob  + (size_t)1024 * 1024;
    unsigned short* ob   = qkvb + (size_t)4096 * 3072;
    unsigned short* vdt  = ob   + (size_t)4096 * 1024;

    cvt_all<<<8192, 256, 0, stream>>>(x, w_qkv, w_out, xb, wqb, wob);

    // qkv = x @ w_qkv^T + b_qkv; Q cols (n<1024) pre-scaled by log2(e)/32
    gemm_nt_mfma<1, 128><<<dim3(24, 32), 256, 0, stream>>>(
        xb, wqb, b_qkv, qkvb, 4096, 3072, 1024, 1024, 0.045084222f);

    vd_transpose<<<dim3(32, 32), 256, 0, stream>>>(qkvb, vdt);

    diff_attn_v6<<<dim3(16, 32), 512, 0, stream>>>(qkvb, vdt, lam, ob);

    gemm_nt_mfma<0, 64><<<dim3(16, 32), 256, 0, stream>>>(
        ob, wob, b_out, out, 4096, 1024, 1024, 0, 1.f);
}

// Round 2
// 186.313 us; speedup vs baseline: 1.0658x; 1.0153x over previous
//
#include <hip/hip_runtime.h>
#include <hip/hip_bf16.h>
#include <stdint.h>

// bf16 MFMA pipeline, v7. B=2, L=2048, D=1024, H=16, dh=64.
// a2 = softmax(s_prev) is a column permutation of a1 -> o = lam * A1 @ (v - roll(v,-1)).
// v7: PV fused to K=32 MFMAs. vdt is stored with a per-32-block j-permutation
// (pos = quad*8 + t*4 + rg for j = t*16 + quad*4 + rg) so the in-register P^T
// (C-layout of S^T) is directly the B-operand of mfma_f32_16x16x32_bf16.
// PV: 16x mfma16 -> 8x mfma32; row-sums: 4x mfma16 -> 2x mfma32;
// V LDS reads: 8x b64 -> 4x b128. Same FLOPs, ~30% fewer MFMA issue slots.

typedef __attribute__((ext_vector_type(8))) short s16x8;
typedef __attribute__((ext_vector_type(4))) short s16x4;
typedef __attribute__((ext_vector_type(4))) float f32x4;
typedef __attribute__((ext_vector_type(4))) unsigned int u32x4;

__device__ __forceinline__ float bf2f(unsigned short u) {
    union { unsigned int i; float f; } x; x.i = ((unsigned int)u) << 16; return x.f;
}
__device__ __forceinline__ unsigned short f2bf(float f) {
    union { float f; unsigned int i; } x; x.f = f;
    unsigned int r = x.i + 0x7FFFu + ((x.i >> 16) & 1u);   // RNE
    return (unsigned short)(r >> 16);
}

// async global->LDS, 16B/lane; LDS dest = wave-uniform base + lane*16
__device__ __forceinline__ void gload16(const void* g, void* l) {
    auto gp = reinterpret_cast<const __attribute__((address_space(1))) unsigned int*>(
        reinterpret_cast<uintptr_t>(g));
    auto lp = reinterpret_cast<__attribute__((address_space(3))) unsigned int*>(
        reinterpret_cast<uintptr_t>(l));
    __builtin_amdgcn_global_load_lds(gp, lp, 16, 0, 0);
}

__global__ __launch_bounds__(256) void cvt_all(
    const float* __restrict__ x, const float* __restrict__ wq,
    const float* __restrict__ wo,
    unsigned short* __restrict__ xb, unsigned short* __restrict__ wqb,
    unsigned short* __restrict__ wob)
{
    int i4 = blockIdx.x * 256 + threadIdx.x;   // float4 index
    const float* src; unsigned short* dst; int off;
    if (i4 < 1048576)            { src = x;  dst = xb;  off = i4; }
    else if (i4 < 1048576 + 786432) { src = wq; dst = wqb; off = i4 - 1048576; }
    else                         { src = wo; dst = wob; off = i4 - 1835008; }
    float4 v = ((const float4*)src)[off];
    ushort4 u;
    u.x = f2bf(v.x); u.y = f2bf(v.y); u.z = f2bf(v.z); u.w = f2bf(v.w);
    ((ushort4*)dst)[off] = u;
}

// vdt[b][h][dh][pos] = v[b, j(pos), h, dh] - v[b, (j(pos)+1)%L, h, dh], transposed
// via LDS. Within each 32-j block, pos(j) = ((j>>2)&3)*8 + ((j>>4)&1)*4 + (j&3),
// i.e. position k = quad*8 + t*4 + rg holds j = t*16 + quad*4 + rg — the exact
// k-layout of the 16x16x32 MFMA A/B operand vs the 16x16 C-layout of S^T.
__global__ __launch_bounds__(256) void vd_transpose(
    const unsigned short* __restrict__ qkvb, unsigned short* __restrict__ vdt)
{
    __shared__ unsigned short T[64][72];
    const int tid = threadIdx.x;
    const int j0 = blockIdx.x * 64;
    const int bh = blockIdx.y, b = bh >> 4, h = bh & 15;
    const unsigned short* vb = qkvb + (size_t)b * 2048 * 3072 + 2048 + h * 64;

    int r = tid >> 2, cq = tid & 3;
    int rp = (r & 35) | ((r & 12) << 1) | ((r & 16) >> 2);   // permuted column
    int j = j0 + r, jn = (j + 1) & 2047;
    const unsigned short* p0 = vb + (size_t)j  * 3072 + cq * 16;
    const unsigned short* p1 = vb + (size_t)jn * 3072 + cq * 16;
    s16x8 a0 = *(const s16x8*)p0, a1 = *(const s16x8*)(p0 + 8);
    s16x8 b0 = *(const s16x8*)p1, b1 = *(const s16x8*)(p1 + 8);
#pragma unroll
    for (int u = 0; u < 8; ++u)
        T[cq * 16 + u][rp] = f2bf(bf2f((unsigned short)a0[u]) - bf2f((unsigned short)b0[u]));
#pragma unroll
    for (int u = 0; u < 8; ++u)
        T[cq * 16 + 8 + u][rp] = f2bf(bf2f((unsigned short)a1[u]) - bf2f((unsigned short)b1[u]));
    __syncthreads();

    int row = tid >> 2, sc = tid & 3;
    s16x8 o0 = *(const s16x8*)&T[row][sc * 16];
    s16x8 o1 = *(const s16x8*)&T[row][sc * 16 + 8];
    unsigned short* dst = vdt + ((size_t)bh * 64 + row) * 2048 + j0 + sc * 16;
    *(s16x8*)dst = o0;
    *(s16x8*)(dst + 8) = o1;
}

// C[m,n] = sum_k A[m,k]*Bm[n,k] + bias[n]; cols < nscale additionally *= smul.
template <int OUT_BF16, int BN>
__global__ __launch_bounds__(256) void gemm_nt_mfma(
    const unsigned short* __restrict__ A,
    const unsigned short* __restrict__ Bm,
    const float* __restrict__ bias,
    void* __restrict__ C,
    int M, int N, int K, int nscale, float smul)
{
    constexpr int NT = BN / 32;
    __shared__ unsigned short As[2][128][32];
    __shared__ unsigned short Bs[2][BN][32];

    const int tid = threadIdx.x;
    const int wave = tid >> 6, lane = tid & 63;
    const int quad = lane >> 4, ln = lane & 15;
    const int wm = (wave >> 1) * 64, wn = (wave & 1) * (NT * 16);
    const int m0 = blockIdx.y * 128, n0 = blockIdx.x * BN;
    const int rA = wave * 16 + (lane >> 2);
    const int gsl = lane & 3;

    f32x4 acc[4][NT];
#pragma unroll
    for (int mt = 0; mt < 4; ++mt)
#pragma unroll
        for (int nt = 0; nt < NT; ++nt) acc[mt][nt] = f32x4{0.f, 0.f, 0.f, 0.f};

    auto stage = [&](int p, int k0) {
#pragma unroll
        for (int q = 0; q < 2; ++q) {
            int row = q * 64 + rA;
            int kg = gsl ^ ((row >> 1) & 3);
            gload16(A + (size_t)(m0 + row) * K + k0 + kg * 8,
                    &As[p][q * 64 + wave * 16][0]);
            if (q * 64 < BN)
                gload16(Bm + (size_t)(n0 + row) * K + k0 + kg * 8,
                        &Bs[p][q * 64 + wave * 16][0]);
        }
    };

    stage(0, 0);
    __syncthreads();
    int p = 0;
    for (int k0 = 0; k0 < K; k0 += 32) {
        if (k0 + 32 < K) stage(p ^ 1, k0 + 32);
        s16x8 af[4], bfr[NT];
#pragma unroll
        for (int mt = 0; mt < 4; ++mt) {
            int rr = wm + mt * 16 + ln;
            af[mt] = *(const s16x8*)&As[p][rr][((quad ^ ((rr >> 1) & 3)) & 3) * 8];
        }
#pragma unroll
        for (int nt = 0; nt < NT; ++nt) {
            int rr = wn + nt * 16 + ln;
            bfr[nt] = *(const s16x8*)&Bs[p][rr][((quad ^ ((rr >> 1) & 3)) & 3) * 8];
        }
#pragma unroll
        for (int mt = 0; mt < 4; ++mt)
#pragma unroll
            for (int nt = 0; nt < NT; ++nt)
                acc[mt][nt] = __builtin_amdgcn_mfma_f32_16x16x32_bf16(
                    af[mt], bfr[nt], acc[mt][nt], 0, 0, 0);
        __syncthreads();
        p ^= 1;
    }

    float bb[NT];
#pragma unroll
    for (int nt = 0; nt < NT; ++nt) bb[nt] = bias[n0 + wn + nt * 16 + ln];
#pragma unroll
    for (int mt = 0; mt < 4; ++mt)
#pragma unroll
        for (int nt = 0; nt < NT; ++nt) {
            int col = n0 + wn + nt * 16 + ln;
            float sc = (col < nscale) ? smul : 1.f;
#pragma unroll
            for (int rg = 0; rg < 4; ++rg) {
                int row = m0 + wm + mt * 16 + quad * 4 + rg;
                float v = (acc[mt][nt][rg] + bb[nt]) * sc;
                if (OUT_BF16)
                    ((unsigned short*)C)[(size_t)row * N + col] = f2bf(v);
                else
                    ((float*)C)[(size_t)row * N + col] = v;
            }
        }
}

// Differential attention, v7: 8 waves (512 thr). wave = jw*4+qw.
// qw owns 32 q-rows; jw in {0,1} owns a 32-row j-half of each 64-row K/V chunk.
// PV and row-sums use K=32 MFMAs (vdt pre-permuted so P^T registers are the
// B-operand verbatim). Cross-jw Ot/lacc reduction through LDS at the end.
__global__ __launch_bounds__(512) void diff_attn_v7(
    const unsigned short* __restrict__ qkv,   // [B*L][3072] bf16 (Q pre-scaled by log2e/32)
    const unsigned short* __restrict__ vdt,   // [B*H][64][2048] bf16, j-permuted per 32-block
    const float* __restrict__ lam_p,
    unsigned short* __restrict__ o_ws)        // [B*L][1024] bf16
{
    constexpr int L = 2048, TD = 3072;

    __shared__ unsigned short Ks[2][64][64];  // [seq][dh], chunk-swizzled
    __shared__ unsigned short Vs[2][64][64];  // [dh][seq-pos], chunk-swizzled
    __shared__ f32x4 Red[4][2][4][64];        // cross-jw Ot reduce: [qw][s][mt][lane]
    __shared__ float Lred[4][2][64];          // cross-jw lacc reduce

    const int tid = threadIdx.x;
    const int wave = tid >> 6, lane = tid & 63;
    const int qw = wave & 3, jw = wave >> 2;
    const int quad = lane >> 4, ln = lane & 15;
    const int bh = blockIdx.y, b = bh >> 4, h = bh & 15;
    const int q0 = blockIdx.x * 128;
    const size_t seqbase = (size_t)b * L;
    const unsigned short* base = qkv + seqbase * TD + h * 64;
    const unsigned short* kb = base + 1024;
    const unsigned short* vbase = vdt + (size_t)bh * 64 * 2048;

    const int lsl = lane >> 3;
    const int cgl = (lane & 7) ^ lsl;

    // Q fragments (layout serves as MFMA B-operand: n=ln -> q, k=quad*8+u -> d)
    s16x8 qf[2][2];
#pragma unroll
    for (int s = 0; s < 2; ++s) {
        const unsigned short* qrow =
            base + (size_t)(q0 + qw * 32 + s * 16 + ln) * TD;
        qf[s][0] = *(const s16x8*)(qrow + quad * 8);
        qf[s][1] = *(const s16x8*)(qrow + 32 + quad * 8);
    }

    // each of 8 waves stages 8 rows of K and 8 rows of Vd^T (1 KiB each)
    auto stage = [&](int p, int j0) {
        const unsigned short* k0p = kb + (size_t)(j0 + wave * 8 + lsl) * TD + cgl * 8;
        gload16(k0p, &Ks[p][wave * 8][0]);
        const unsigned short* v0p = vbase + (size_t)(wave * 8 + lsl) * 2048 + j0 + cgl * 8;
        gload16(v0p, &Vs[p][wave * 8][0]);
    };

    f32x4 Ot[2][4];    // O^T accumulators: q=ln, d = mt*16 + quad*4 + rg
    f32x4 lacc[2];     // row-sum accumulators via ones-MFMA (all rg equal)
#pragma unroll
    for (int s = 0; s < 2; ++s) {
        lacc[s] = f32x4{0.f, 0.f, 0.f, 0.f};
#pragma unroll
        for (int mt = 0; mt < 4; ++mt) Ot[s][mt] = f32x4{0.f, 0.f, 0.f, 0.f};
    }

    const s16x8 ones8 = {(short)0x3F80, (short)0x3F80, (short)0x3F80, (short)0x3F80,
                         (short)0x3F80, (short)0x3F80, (short)0x3F80, (short)0x3F80};
    const int kx0 = (quad ^ (ln & 7)) << 3;
    const int kx1 = ((quad + 4) ^ (ln & 7)) << 3;
    const int vx  = (((jw * 4 + quad) ^ (ln & 7))) << 3;   // V chunk for this wave's j-half

    stage(0, 0);
    __syncthreads();
    int p = 0;
    for (int kt = 0; kt < 32; ++kt) {
        if (kt + 1 < 32) stage(p ^ 1, (kt + 1) * 64);

        // ---- S^T = K Q^T over this wave's j-half (t2 = jw*2 + t, t in {0,1}) ----
        // A = K-frag (m=j), B = qf (n=q). C: col=ln->q, row=quad*4+rg->j
        f32x4 ST[2][2];
#pragma unroll
        for (int t = 0; t < 2; ++t) {
            const int t2 = jw * 2 + t;
            s16x8 k0 = *(const s16x8*)&Ks[p][t2 * 16 + ln][kx0];
            s16x8 k1 = *(const s16x8*)&Ks[p][t2 * 16 + ln][kx1];
#pragma unroll
            for (int s = 0; s < 2; ++s) {
                f32x4 z = f32x4{0.f, 0.f, 0.f, 0.f};
                z = __builtin_amdgcn_mfma_f32_16x16x32_bf16(k0, qf[s][0], z, 0, 0, 0);
                z = __builtin_amdgcn_mfma_f32_16x16x32_bf16(k1, qf[s][1], z, 0, 0, 0);
                ST[s][t] = z;
            }
        }

        // ---- P'^T = exp2(S^T) packed to bf16 in-register as K=32 B-frag ----
        // element u = t*4+rg at chunk quad -> k = quad*8+u, which vdt's
        // j-permutation defines as j = t*16 + quad*4 + rg. Exact match.
        s16x8 pf8[2];
#pragma unroll
        for (int s = 0; s < 2; ++s) {
            unsigned int w[4];
#pragma unroll
            for (int t = 0; t < 2; ++t) {
                unsigned int b0 = __builtin_bit_cast(unsigned int,
                    __builtin_amdgcn_exp2f(ST[s][t][0]));
                unsigned int b1 = __builtin_bit_cast(unsigned int,
                    __builtin_amdgcn_exp2f(ST[s][t][1]));
                unsigned int b2 = __builtin_bit_cast(unsigned int,
                    __builtin_amdgcn_exp2f(ST[s][t][2]));
                unsigned int b3 = __builtin_bit_cast(unsigned int,
                    __builtin_amdgcn_exp2f(ST[s][t][3]));
                w[t * 2]     = (b0 >> 16) | (b1 & 0xFFFF0000u);
                w[t * 2 + 1] = (b2 >> 16) | (b3 & 0xFFFF0000u);
            }
            pf8[s] = __builtin_bit_cast(s16x8, (u32x4){w[0], w[1], w[2], w[3]});
        }

        // ---- partial row sums l[q] += sum_j P^T[j][q] via ones-MFMA (K=32) ----
#pragma unroll
        for (int s = 0; s < 2; ++s)
            lacc[s] = __builtin_amdgcn_mfma_f32_16x16x32_bf16(
                ones8, pf8[s], lacc[s], 0, 0, 0);

        // ---- O^T += Vd'^T P'^T over this wave's j-half (K=32) ----
#pragma unroll
        for (int mt = 0; mt < 4; ++mt) {
            s16x8 vf = *(const s16x8*)&Vs[p][mt * 16 + ln][vx];
#pragma unroll
            for (int s = 0; s < 2; ++s)
                Ot[s][mt] = __builtin_amdgcn_mfma_f32_16x16x32_bf16(
                    vf, pf8[s], Ot[s][mt], 0, 0, 0);
        }
        __syncthreads();
        p ^= 1;
    }

    // ---- cross-jw reduction through LDS, then epilogue by jw==0 waves ----
    if (jw == 1) {
#pragma unroll
        for (int s = 0; s < 2; ++s) {
            Lred[qw][s][lane] = lacc[s][0];
#pragma unroll
            for (int mt = 0; mt < 4; ++mt) Red[qw][s][mt][lane] = Ot[s][mt];
        }
    }
    __syncthreads();
    if (jw == 0) {
        const float lam = lam_p[0];
#pragma unroll
        for (int s = 0; s < 2; ++s) {
            float lsum = lacc[s][0] + Lred[qw][s][lane];
            float inv = lam / lsum;
            int row = q0 + qw * 32 + s * 16 + ln;
            unsigned short* orow = o_ws + (seqbase + row) * 1024 + h * 64 + quad * 4;
#pragma unroll
            for (int mt = 0; mt < 4; ++mt) {
                f32x4 r = Red[qw][s][mt][lane];
                ushort4 u;
                u.x = f2bf((Ot[s][mt][0] + r[0]) * inv);
                u.y = f2bf((Ot[s][mt][1] + r[1]) * inv);
                u.z = f2bf((Ot[s][mt][2] + r[2]) * inv);
                u.w = f2bf((Ot[s][mt][3] + r[3]) * inv);
                *(ushort4*)(orow + mt * 16) = u;
            }
        }
    }
}

extern "C" void kernel_launch(void* const* d_in, const int* in_sizes, int n_in,
                              void* d_out, int out_size, void* d_ws, size_t ws_size,
                              hipStream_t stream) {
    const float* x     = (const float*)d_in[0];
    const float* w_qkv = (const float*)d_in[1];
    const float* b_qkv = (const float*)d_in[2];
    const float* w_out = (const float*)d_in[3];
    const float* b_out = (const float*)d_in[4];
    const float* lam   = (const float*)d_in[5];
    float* out = (float*)d_out;

    unsigned short* xb   = (unsigned short*)d_ws;
    unsigned short* wqb  = xb   + (size_t)4096 * 1024;
    unsigned short* wob  = wqb  + (size_t)3072 * 1024;
    unsigned short* qkvb = wob  + (size_t)1024 * 1024;
    unsigned short* ob   = qkvb + (size_t)4096 * 3072;
    unsigned short* vdt  = ob   + (size_t)4096 * 1024;

    cvt_all<<<8192, 256, 0, stream>>>(x, w_qkv, w_out, xb, wqb, wob);

    // qkv = x @ w_qkv^T + b_qkv; Q cols (n<1024) pre-scaled by log2(e)/32
    gemm_nt_mfma<1, 128><<<dim3(24, 32), 256, 0, stream>>>(
        xb, wqb, b_qkv, qkvb, 4096, 3072, 1024, 1024, 0.045084222f);

    vd_transpose<<<dim3(32, 32), 256, 0, stream>>>(qkvb, vdt);

    diff_attn_v7<<<dim3(16, 32), 512, 0, stream>>>(qkvb, vdt, lam, ob);

    gemm_nt_mfma<0, 64><<<dim3(16, 32), 256, 0, stream>>>(
        ob, wob, b_out, out, 4096, 1024, 1024, 0, 1.f);
}

// Round 3
// 181.823 us; speedup vs baseline: 1.0922x; 1.0247x over previous
//
#include <hip/hip_runtime.h>
#include <hip/hip_bf16.h>
#include <stdint.h>

// bf16 MFMA pipeline, v8. B=2, L=2048, D=1024, H=16, dh=64.
// a2 = softmax(s_prev) is a column permutation of a1 -> o = lam * A1 @ (v - roll(v,-1)).
// v8: attention K/V staging deep-pipelined (T3/T4): 3 LDS buffers, stage issued
// 2 tiles ahead, per-kt sync = s_waitcnt vmcnt(2) + raw s_barrier (never drain
// to 0 in the loop). Cross-jw reduction scratch aliased onto staging buffers
// (live only after the loop) -> LDS 66KB -> 48KB.

typedef __attribute__((ext_vector_type(8))) short s16x8;
typedef __attribute__((ext_vector_type(4))) short s16x4;
typedef __attribute__((ext_vector_type(4))) float f32x4;
typedef __attribute__((ext_vector_type(4))) unsigned int u32x4;

__device__ __forceinline__ float bf2f(unsigned short u) {
    union { unsigned int i; float f; } x; x.i = ((unsigned int)u) << 16; return x.f;
}
__device__ __forceinline__ unsigned short f2bf(float f) {
    union { float f; unsigned int i; } x; x.f = f;
    unsigned int r = x.i + 0x7FFFu + ((x.i >> 16) & 1u);   // RNE
    return (unsigned short)(r >> 16);
}

// async global->LDS, 16B/lane; LDS dest = wave-uniform base + lane*16
__device__ __forceinline__ void gload16(const void* g, void* l) {
    auto gp = reinterpret_cast<const __attribute__((address_space(1))) unsigned int*>(
        reinterpret_cast<uintptr_t>(g));
    auto lp = reinterpret_cast<__attribute__((address_space(3))) unsigned int*>(
        reinterpret_cast<uintptr_t>(l));
    __builtin_amdgcn_global_load_lds(gp, lp, 16, 0, 0);
}

__global__ __launch_bounds__(256) void cvt_all(
    const float* __restrict__ x, const float* __restrict__ wq,
    const float* __restrict__ wo,
    unsigned short* __restrict__ xb, unsigned short* __restrict__ wqb,
    unsigned short* __restrict__ wob)
{
    int i4 = blockIdx.x * 256 + threadIdx.x;   // float4 index
    const float* src; unsigned short* dst; int off;
    if (i4 < 1048576)            { src = x;  dst = xb;  off = i4; }
    else if (i4 < 1048576 + 786432) { src = wq; dst = wqb; off = i4 - 1048576; }
    else                         { src = wo; dst = wob; off = i4 - 1835008; }
    float4 v = ((const float4*)src)[off];
    ushort4 u;
    u.x = f2bf(v.x); u.y = f2bf(v.y); u.z = f2bf(v.z); u.w = f2bf(v.w);
    ((ushort4*)dst)[off] = u;
}

// vdt[b][h][dh][pos] = v[b, j(pos), h, dh] - v[b, (j(pos)+1)%L, h, dh], transposed
// via LDS. Within each 32-j block, pos(j) = ((j>>2)&3)*8 + ((j>>4)&1)*4 + (j&3),
// i.e. position k = quad*8 + t*4 + rg holds j = t*16 + quad*4 + rg — the exact
// k-layout of the 16x16x32 MFMA A/B operand vs the 16x16 C-layout of S^T.
__global__ __launch_bounds__(256) void vd_transpose(
    const unsigned short* __restrict__ qkvb, unsigned short* __restrict__ vdt)
{
    __shared__ unsigned short T[64][72];
    const int tid = threadIdx.x;
    const int j0 = blockIdx.x * 64;
    const int bh = blockIdx.y, b = bh >> 4, h = bh & 15;
    const unsigned short* vb = qkvb + (size_t)b * 2048 * 3072 + 2048 + h * 64;

    int r = tid >> 2, cq = tid & 3;
    int rp = (r & 35) | ((r & 12) << 1) | ((r & 16) >> 2);   // permuted column
    int j = j0 + r, jn = (j + 1) & 2047;
    const unsigned short* p0 = vb + (size_t)j  * 3072 + cq * 16;
    const unsigned short* p1 = vb + (size_t)jn * 3072 + cq * 16;
    s16x8 a0 = *(const s16x8*)p0, a1 = *(const s16x8*)(p0 + 8);
    s16x8 b0 = *(const s16x8*)p1, b1 = *(const s16x8*)(p1 + 8);
#pragma unroll
    for (int u = 0; u < 8; ++u)
        T[cq * 16 + u][rp] = f2bf(bf2f((unsigned short)a0[u]) - bf2f((unsigned short)b0[u]));
#pragma unroll
    for (int u = 0; u < 8; ++u)
        T[cq * 16 + 8 + u][rp] = f2bf(bf2f((unsigned short)a1[u]) - bf2f((unsigned short)b1[u]));
    __syncthreads();

    int row = tid >> 2, sc = tid & 3;
    s16x8 o0 = *(const s16x8*)&T[row][sc * 16];
    s16x8 o1 = *(const s16x8*)&T[row][sc * 16 + 8];
    unsigned short* dst = vdt + ((size_t)bh * 64 + row) * 2048 + j0 + sc * 16;
    *(s16x8*)dst = o0;
    *(s16x8*)(dst + 8) = o1;
}

// C[m,n] = sum_k A[m,k]*Bm[n,k] + bias[n]; cols < nscale additionally *= smul.
template <int OUT_BF16, int BN>
__global__ __launch_bounds__(256) void gemm_nt_mfma(
    const unsigned short* __restrict__ A,
    const unsigned short* __restrict__ Bm,
    const float* __restrict__ bias,
    void* __restrict__ C,
    int M, int N, int K, int nscale, float smul)
{
    constexpr int NT = BN / 32;
    __shared__ unsigned short As[2][128][32];
    __shared__ unsigned short Bs[2][BN][32];

    const int tid = threadIdx.x;
    const int wave = tid >> 6, lane = tid & 63;
    const int quad = lane >> 4, ln = lane & 15;
    const int wm = (wave >> 1) * 64, wn = (wave & 1) * (NT * 16);
    const int m0 = blockIdx.y * 128, n0 = blockIdx.x * BN;
    const int rA = wave * 16 + (lane >> 2);
    const int gsl = lane & 3;

    f32x4 acc[4][NT];
#pragma unroll
    for (int mt = 0; mt < 4; ++mt)
#pragma unroll
        for (int nt = 0; nt < NT; ++nt) acc[mt][nt] = f32x4{0.f, 0.f, 0.f, 0.f};

    auto stage = [&](int p, int k0) {
#pragma unroll
        for (int q = 0; q < 2; ++q) {
            int row = q * 64 + rA;
            int kg = gsl ^ ((row >> 1) & 3);
            gload16(A + (size_t)(m0 + row) * K + k0 + kg * 8,
                    &As[p][q * 64 + wave * 16][0]);
            if (q * 64 < BN)
                gload16(Bm + (size_t)(n0 + row) * K + k0 + kg * 8,
                        &Bs[p][q * 64 + wave * 16][0]);
        }
    };

    stage(0, 0);
    __syncthreads();
    int p = 0;
    for (int k0 = 0; k0 < K; k0 += 32) {
        if (k0 + 32 < K) stage(p ^ 1, k0 + 32);
        s16x8 af[4], bfr[NT];
#pragma unroll
        for (int mt = 0; mt < 4; ++mt) {
            int rr = wm + mt * 16 + ln;
            af[mt] = *(const s16x8*)&As[p][rr][((quad ^ ((rr >> 1) & 3)) & 3) * 8];
        }
#pragma unroll
        for (int nt = 0; nt < NT; ++nt) {
            int rr = wn + nt * 16 + ln;
            bfr[nt] = *(const s16x8*)&Bs[p][rr][((quad ^ ((rr >> 1) & 3)) & 3) * 8];
        }
#pragma unroll
        for (int mt = 0; mt < 4; ++mt)
#pragma unroll
            for (int nt = 0; nt < NT; ++nt)
                acc[mt][nt] = __builtin_amdgcn_mfma_f32_16x16x32_bf16(
                    af[mt], bfr[nt], acc[mt][nt], 0, 0, 0);
        __syncthreads();
        p ^= 1;
    }

    float bb[NT];
#pragma unroll
    for (int nt = 0; nt < NT; ++nt) bb[nt] = bias[n0 + wn + nt * 16 + ln];
#pragma unroll
    for (int mt = 0; mt < 4; ++mt)
#pragma unroll
        for (int nt = 0; nt < NT; ++nt) {
            int col = n0 + wn + nt * 16 + ln;
            float sc = (col < nscale) ? smul : 1.f;
#pragma unroll
            for (int rg = 0; rg < 4; ++rg) {
                int row = m0 + wm + mt * 16 + quad * 4 + rg;
                float v = (acc[mt][nt][rg] + bb[nt]) * sc;
                if (OUT_BF16)
                    ((unsigned short*)C)[(size_t)row * N + col] = f2bf(v);
                else
                    ((float*)C)[(size_t)row * N + col] = v;
            }
        }
}

// Differential attention, v8: 8 waves (512 thr). wave = jw*4+qw.
// qw owns 32 q-rows; jw in {0,1} owns a 32-row j-half of each 64-row K/V chunk.
// 3-buffer K/V staging, 2-deep prefetch, counted vmcnt(2) + raw s_barrier.
// Cross-jw Ot/lacc reduction aliased onto staging LDS after the loop.
__global__ __launch_bounds__(512) void diff_attn_v8(
    const unsigned short* __restrict__ qkv,   // [B*L][3072] bf16 (Q pre-scaled by log2e/32)
    const unsigned short* __restrict__ vdt,   // [B*H][64][2048] bf16, j-permuted per 32-block
    const float* __restrict__ lam_p,
    unsigned short* __restrict__ o_ws)        // [B*L][1024] bf16
{
    constexpr int L = 2048, TD = 3072;

    // 48 KiB: [0,24576) = Ks[3][64][64], [24576,49152) = Vs[3][64][64].
    // After the kt loop (full __syncthreads drain) the same space is reused as
    // Red[4][2][4][64] (f32x4, 32 KiB) + Lred[4][2][64] (2 KiB @ offset 32768).
    __shared__ __align__(16) unsigned char smem[49152];
    auto Ks = reinterpret_cast<unsigned short(*)[64][64]>(smem);
    auto Vs = reinterpret_cast<unsigned short(*)[64][64]>(smem + 24576);
    auto Red = reinterpret_cast<f32x4(*)[2][4][64]>(smem);
    auto Lred = reinterpret_cast<float(*)[2][64]>(smem + 32768);

    const int tid = threadIdx.x;
    const int wave = tid >> 6, lane = tid & 63;
    const int qw = wave & 3, jw = wave >> 2;
    const int quad = lane >> 4, ln = lane & 15;
    const int bh = blockIdx.y, b = bh >> 4, h = bh & 15;
    const int q0 = blockIdx.x * 128;
    const size_t seqbase = (size_t)b * L;
    const unsigned short* base = qkv + seqbase * TD + h * 64;
    const unsigned short* kb = base + 1024;
    const unsigned short* vbase = vdt + (size_t)bh * 64 * 2048;

    const int lsl = lane >> 3;
    const int cgl = (lane & 7) ^ lsl;

    // lam: load and force-retire before the loop so the loop's vmem queue holds
    // ONLY the staging loads (vmcnt(2) accounting depends on this).
    const float lam = lam_p[0];
    asm volatile("" :: "v"(lam));

    // Q fragments (layout serves as MFMA B-operand: n=ln -> q, k=quad*8+u -> d)
    s16x8 qf[2][2];
#pragma unroll
    for (int s = 0; s < 2; ++s) {
        const unsigned short* qrow =
            base + (size_t)(q0 + qw * 32 + s * 16 + ln) * TD;
        qf[s][0] = *(const s16x8*)(qrow + quad * 8);
        qf[s][1] = *(const s16x8*)(qrow + 32 + quad * 8);
    }

    // each of 8 waves stages 8 rows of K and 8 rows of Vd^T (1 KiB each); 2 vmem ops
    auto stage = [&](int p, int j0) {
        const unsigned short* k0p = kb + (size_t)(j0 + wave * 8 + lsl) * TD + cgl * 8;
        gload16(k0p, &Ks[p][wave * 8][0]);
        const unsigned short* v0p = vbase + (size_t)(wave * 8 + lsl) * 2048 + j0 + cgl * 8;
        gload16(v0p, &Vs[p][wave * 8][0]);
    };

    f32x4 Ot[2][4];    // O^T accumulators: q=ln, d = mt*16 + quad*4 + rg
    f32x4 lacc[2];     // row-sum accumulators via ones-MFMA (all rg equal)
#pragma unroll
    for (int s = 0; s < 2; ++s) {
        lacc[s] = f32x4{0.f, 0.f, 0.f, 0.f};
#pragma unroll
        for (int mt = 0; mt < 4; ++mt) Ot[s][mt] = f32x4{0.f, 0.f, 0.f, 0.f};
    }

    const s16x8 ones8 = {(short)0x3F80, (short)0x3F80, (short)0x3F80, (short)0x3F80,
                         (short)0x3F80, (short)0x3F80, (short)0x3F80, (short)0x3F80};
    const int kx0 = (quad ^ (ln & 7)) << 3;
    const int kx1 = ((quad + 4) ^ (ln & 7)) << 3;
    const int vx  = (((jw * 4 + quad) ^ (ln & 7))) << 3;   // V chunk for this wave's j-half

    // prologue: buffers 0 and 1 in flight (4 outstanding vmem/wave)
    stage(0, 0);
    stage(1, 64);
    asm volatile("s_waitcnt vmcnt(2)" ::: "memory");   // buffer 0 ready
    __builtin_amdgcn_s_barrier();

    int cur = 0, nx2 = 2;                              // nx2 = (kt+2) % 3
    for (int kt = 0; kt < 32; ++kt) {
        // stage tile kt+2 (j0 wraps mod L in the last 2 iters: discarded data,
        // keeps the vmcnt accounting uniform at 2 outstanding)
        stage(nx2, ((kt + 2) & 31) * 64);

        // ---- S^T = K Q^T over this wave's j-half (t2 = jw*2 + t, t in {0,1}) ----
        // A = K-frag (m=j), B = qf (n=q). C: col=ln->q, row=quad*4+rg->j
        f32x4 ST[2][2];
#pragma unroll
        for (int t = 0; t < 2; ++t) {
            const int t2 = jw * 2 + t;
            s16x8 k0 = *(const s16x8*)&Ks[cur][t2 * 16 + ln][kx0];
            s16x8 k1 = *(const s16x8*)&Ks[cur][t2 * 16 + ln][kx1];
#pragma unroll
            for (int s = 0; s < 2; ++s) {
                f32x4 z = f32x4{0.f, 0.f, 0.f, 0.f};
                z = __builtin_amdgcn_mfma_f32_16x16x32_bf16(k0, qf[s][0], z, 0, 0, 0);
                z = __builtin_amdgcn_mfma_f32_16x16x32_bf16(k1, qf[s][1], z, 0, 0, 0);
                ST[s][t] = z;
            }
        }

        // ---- P'^T = exp2(S^T) packed to bf16 in-register as K=32 B-frag ----
        // element u = t*4+rg at chunk quad -> k = quad*8+u, which vdt's
        // j-permutation defines as j = t*16 + quad*4 + rg. Exact match.
        s16x8 pf8[2];
#pragma unroll
        for (int s = 0; s < 2; ++s) {
            unsigned int w[4];
#pragma unroll
            for (int t = 0; t < 2; ++t) {
                unsigned int b0 = __builtin_bit_cast(unsigned int,
                    __builtin_amdgcn_exp2f(ST[s][t][0]));
                unsigned int b1 = __builtin_bit_cast(unsigned int,
                    __builtin_amdgcn_exp2f(ST[s][t][1]));
                unsigned int b2 = __builtin_bit_cast(unsigned int,
                    __builtin_amdgcn_exp2f(ST[s][t][2]));
                unsigned int b3 = __builtin_bit_cast(unsigned int,
                    __builtin_amdgcn_exp2f(ST[s][t][3]));
                w[t * 2]     = (b0 >> 16) | (b1 & 0xFFFF0000u);
                w[t * 2 + 1] = (b2 >> 16) | (b3 & 0xFFFF0000u);
            }
            pf8[s] = __builtin_bit_cast(s16x8, (u32x4){w[0], w[1], w[2], w[3]});
        }

        // ---- partial row sums l[q] += sum_j P^T[j][q] via ones-MFMA (K=32) ----
#pragma unroll
        for (int s = 0; s < 2; ++s)
            lacc[s] = __builtin_amdgcn_mfma_f32_16x16x32_bf16(
                ones8, pf8[s], lacc[s], 0, 0, 0);

        // ---- O^T += Vd'^T P'^T over this wave's j-half (K=32) ----
#pragma unroll
        for (int mt = 0; mt < 4; ++mt) {
            s16x8 vf = *(const s16x8*)&Vs[cur][mt * 16 + ln][vx];
#pragma unroll
            for (int s = 0; s < 2; ++s)
                Ot[s][mt] = __builtin_amdgcn_mfma_f32_16x16x32_bf16(
                    vf, pf8[s], Ot[s][mt], 0, 0, 0);
        }

        // counted wait: keep tile kt+2's 2 loads in flight; tile kt+1 complete.
        asm volatile("s_waitcnt vmcnt(2)" ::: "memory");
        __builtin_amdgcn_s_barrier();
        asm volatile("" ::: "memory");

        cur = (cur == 2) ? 0 : cur + 1;
        nx2 = (nx2 == 2) ? 0 : nx2 + 1;
    }

    // full drain (trailing wrap-stage loads) before aliasing LDS as Red/Lred
    __syncthreads();

    // ---- cross-jw reduction through LDS, then epilogue by jw==0 waves ----
    if (jw == 1) {
#pragma unroll
        for (int s = 0; s < 2; ++s) {
            Lred[qw][s][lane] = lacc[s][0];
#pragma unroll
            for (int mt = 0; mt < 4; ++mt) Red[qw][s][mt][lane] = Ot[s][mt];
        }
    }
    __syncthreads();
    if (jw == 0) {
#pragma unroll
        for (int s = 0; s < 2; ++s) {
            float lsum = lacc[s][0] + Lred[qw][s][lane];
            float inv = lam / lsum;
            int row = q0 + qw * 32 + s * 16 + ln;
            unsigned short* orow = o_ws + (seqbase + row) * 1024 + h * 64 + quad * 4;
#pragma unroll
            for (int mt = 0; mt < 4; ++mt) {
                f32x4 r = Red[qw][s][mt][lane];
                ushort4 u;
                u.x = f2bf((Ot[s][mt][0] + r[0]) * inv);
                u.y = f2bf((Ot[s][mt][1] + r[1]) * inv);
                u.z = f2bf((Ot[s][mt][2] + r[2]) * inv);
                u.w = f2bf((Ot[s][mt][3] + r[3]) * inv);
                *(ushort4*)(orow + mt * 16) = u;
            }
        }
    }
}

extern "C" void kernel_launch(void* const* d_in, const int* in_sizes, int n_in,
                              void* d_out, int out_size, void* d_ws, size_t ws_size,
                              hipStream_t stream) {
    const float* x     = (const float*)d_in[0];
    const float* w_qkv = (const float*)d_in[1];
    const float* b_qkv = (const float*)d_in[2];
    const float* w_out = (const float*)d_in[3];
    const float* b_out = (const float*)d_in[4];
    const float* lam   = (const float*)d_in[5];
    float* out = (float*)d_out;

    unsigned short* xb   = (unsigned short*)d_ws;
    unsigned short* wqb  = xb   + (size_t)4096 * 1024;
    unsigned short* wob  = wqb  + (size_t)3072 * 1024;
    unsigned short* qkvb = wob  + (size_t)1024 * 1024;
    unsigned short* ob   = qkvb + (size_t)4096 * 3072;
    unsigned short* vdt  = ob   + (size_t)4096 * 1024;

    cvt_all<<<8192, 256, 0, stream>>>(x, w_qkv, w_out, xb, wqb, wob);

    // qkv = x @ w_qkv^T + b_qkv; Q cols (n<1024) pre-scaled by log2(e)/32
    gemm_nt_mfma<1, 128><<<dim3(24, 32), 256, 0, stream>>>(
        xb, wqb, b_qkv, qkvb, 4096, 3072, 1024, 1024, 0.045084222f);

    vd_transpose<<<dim3(32, 32), 256, 0, stream>>>(qkvb, vdt);

    diff_attn_v8<<<dim3(16, 32), 512, 0, stream>>>(qkvb, vdt, lam, ob);

    gemm_nt_mfma<0, 64><<<dim3(16, 32), 256, 0, stream>>>(
        ob, wob, b_out, out, 4096, 1024, 1024, 0, 1.f);
}